// Round 7
// baseline (537.260 us; speedup 1.0000x reference)
//
#include <hip/hip_runtime.h>
#include <math.h>

#define NEG_SLOPE 0.2f

typedef short s16x4 __attribute__((ext_vector_type(4)));
typedef short s16x8 __attribute__((ext_vector_type(8)));
typedef float f32x16 __attribute__((ext_vector_type(16)));
typedef _Float16 f16x2 __attribute__((ext_vector_type(2)));
typedef _Float16 f16x4 __attribute__((ext_vector_type(4)));
typedef _Float16 f16x8 __attribute__((ext_vector_type(8)));

#define PAIR(v,i) __builtin_shufflevector(v, v, 2*(i), 2*(i)+1)

// float -> bf16 (round-to-nearest-even), and back
__device__ __forceinline__ unsigned short f2bf(float x){
  unsigned int u = __float_as_uint(x);
  unsigned int r = u + 0x7FFFu + ((u >> 16) & 1u);
  return (unsigned short)(r >> 16);
}
__device__ __forceinline__ float bf2f(unsigned short h){
  return __uint_as_float(((unsigned int)h) << 16);
}

// ---------------------------------------------------------------- CSR build
__global__ void deg_count_kernel(const int* __restrict__ dst, int* __restrict__ deg, int E){
  int e = blockIdx.x * blockDim.x + threadIdx.x;
  if (e < E) atomicAdd(&deg[dst[e]], 1);
}

// block-scan prefix allocation (196 atomics total) instead of 50k
// same-address atomics (serialized at L2).
__global__ __launch_bounds__(256) void base_assign_kernel(
    const int* __restrict__ deg, int* __restrict__ base,
    int* __restrict__ counter, int N){
  __shared__ int wsum[4];
  __shared__ int bbase;
  int n = blockIdx.x * 256 + threadIdx.x;
  int d = (n < N) ? deg[n] : 0;
  int lane = threadIdx.x & 63;
  int wid  = threadIdx.x >> 6;
  int scan = d;
  #pragma unroll
  for (int o = 1; o < 64; o <<= 1){
    int t = __shfl_up(scan, o);
    if (lane >= o) scan += t;
  }
  if (lane == 63) wsum[wid] = scan;
  __syncthreads();
  if (threadIdx.x == 0){
    int tot = 0;
    #pragma unroll
    for (int i = 0; i < 4; i++){ int w = wsum[i]; wsum[i] = tot; tot += w; }
    bbase = atomicAdd(counter, tot);
  }
  __syncthreads();
  if (n < N) base[n] = bbase + wsum[wid] + scan - d;
}

// ea stored as broadcast half2 bits (h | h<<16) -- the agg reads it as
// f16x2 with zero per-edge conversion cost.
__global__ void fill_kernel(const int* __restrict__ ei, const float* __restrict__ ea,
                            const int* __restrict__ base, int* __restrict__ pos,
                            int2* __restrict__ csr_pack, int E){
  int e = blockIdx.x * blockDim.x + threadIdx.x;
  if (e >= E) return;
  int s = ei[e], d = ei[E + e];
  int p = atomicAdd(&pos[d], 1);
  _Float16 h = (_Float16)ea[e];
  unsigned int hb = (unsigned int)*(unsigned short*)&h;
  csr_pack[base[d] + p] = make_int2(s, (int)(hb | (hb << 16)));
}

// ---------------------------------------------------------------- weight prep
// Pack W1|W2 (each [K][NOUT] fp32 row-major) into bf16 hi/lo arrays laid out as
// [kgroup][col(2*NOUT)][8 k-elems] -- exactly the MFMA B-fragment order, so the
// GEMM reads B fragments as fully-coalesced 16B-per-lane global loads.
__device__ __forceinline__ void pack_pair(const float* __restrict__ W1,
                                          const float* __restrict__ W2,
                                          short* __restrict__ H, short* __restrict__ L,
                                          int id, int K, int NOUT){
  int BN = 2 * NOUT;
  int kg = id / BN, cb = id - kg * BN;
  const float* W = (cb < NOUT) ? W1 : W2;
  int c = (cb < NOUT) ? cb : cb - NOUT;
  s16x8 hv, lv;
  #pragma unroll
  for (int e = 0; e < 8; e++){
    int k = kg * 8 + e;
    float v = (k < K) ? W[(long)k * NOUT + c] : 0.f;
    unsigned short h = f2bf(v);
    hv[e] = (short)h;
    lv[e] = (short)f2bf(v - bf2f(h));
  }
  *(s16x8*)&H[(long)id * 8] = hv;
  *(s16x8*)&L[(long)id * 8] = lv;
}

__global__ void prep_w_kernel(const float* Wl1, const float* Wr1, short* H1, short* L1,
                              const float* Wl2, const float* Wr2, short* H2, short* L2,
                              const float* Wl3, const float* Wr3, short* H3, short* L3,
                              const float* Wl4, const float* Wr4, short* H4, short* L4){
  int id = blockIdx.x * blockDim.x + threadIdx.x;
  if (id < 512)  { pack_pair(Wl1, Wr1, H1, L1, id, 15, 128); return; }   // KG=2,  BN=256
  id -= 512;
  if (id < 4096) { pack_pair(Wl2, Wr2, H2, L2, id, 128, 128); return; }  // KG=16, BN=256
  id -= 4096;
  if (id < 4096) { pack_pair(Wl3, Wr3, H3, L3, id, 128, 128); return; }
  id -= 4096;
  if (id < 2048) { pack_pair(Wl4, Wr4, H4, L4, id, 128, 64); return; }   // KG=16, BN=128
}

// ---------------------------------------------------------------- MFMA dual GEMM (layer 1, K=15)
// A gathered+converted in-kernel (cheap at K=15: 1 kstep). Outputs fp16:
// xl/xr are only consumed by the agg (attention values); precision path to the
// next gemm flows through the agg's bf16 hi/lo pack, not these.
// Fragment layouts (gfx950 v_mfma_f32_32x32x16_bf16):
//   A: row = lane&31, k = 8*(lane>>5)+e     B: col = lane&31, k = 8*(lane>>5)+e
//   D: col = lane&31, row = (reg&3) + 8*(reg>>2) + 4*(lane>>5)
template<int NOUT, int K>
__global__ __launch_bounds__(256) void gemm_dual_mfma(
    const float* __restrict__ X,
    const short* __restrict__ BH, const short* __restrict__ BL,
    const float* __restrict__ b1, const float* __restrict__ b2,
    _Float16* __restrict__ Y1, _Float16* __restrict__ Y2, int N)
{
  constexpr int BN     = 2 * NOUT;
  constexpr int KSTEPS = (K + 15) / 16;     // one 32x32x16 MFMA step each
  constexpr int NR     = NOUT / 32;         // col fragments per wave (4 or 2)

  int tid   = threadIdx.x;
  int lane  = tid & 63;
  int wid   = tid >> 6;
  int wm    = wid >> 1, wn = wid & 1;       // block = 64 rows x (Y1|Y2)
  int llane = lane & 31, hlane = lane >> 5;
  int r0    = blockIdx.x * 64;

  // ---- A: load this lane's row (half-K per lane-half), convert hi/lo once
  int arow  = r0 + wm * 32 + llane;
  bool rv   = arow < N;
  const float* px = X + (long)arow * K;

  s16x8 ah[KSTEPS], al[KSTEPS];
  #pragma unroll
  for (int ks = 0; ks < KSTEPS; ks++){
    int kg = (2 * ks + hlane) * 8;
    float v[8];
    if constexpr (K % 8 == 0){
      float4 p0 = {0.f,0.f,0.f,0.f}, p1 = {0.f,0.f,0.f,0.f};
      if (rv){
        p0 = *(const float4*)(px + kg);
        p1 = *(const float4*)(px + kg + 4);
      }
      v[0]=p0.x; v[1]=p0.y; v[2]=p0.z; v[3]=p0.w;
      v[4]=p1.x; v[5]=p1.y; v[6]=p1.z; v[7]=p1.w;
    } else {
      #pragma unroll
      for (int e = 0; e < 8; e++)
        v[e] = (rv && kg + e < K) ? px[kg + e] : 0.f;
    }
    #pragma unroll
    for (int e = 0; e < 8; e++){
      unsigned short h = f2bf(v[e]);
      ah[ks][e] = (short)h;
      al[ks][e] = (short)f2bf(v[e] - bf2f(h));
    }
  }

  f32x16 acc[NR];
  #pragma unroll
  for (int n = 0; n < NR; n++)
    #pragma unroll
    for (int i = 0; i < 16; i++) acc[n][i] = 0.f;

  const s16x8* BHf = (const s16x8*)BH;
  const s16x8* BLf = (const s16x8*)BL;
  #pragma unroll
  for (int ks = 0; ks < KSTEPS; ks++){
    long fb = (long)(2 * ks + hlane) * BN + wn * NOUT + llane;
    s16x8 bh[NR], bl[NR];
    #pragma unroll
    for (int n = 0; n < NR; n++){
      bh[n] = BHf[fb + n * 32];
      bl[n] = BLf[fb + n * 32];
    }
    #pragma unroll
    for (int n = 0; n < NR; n++)
      acc[n] = __builtin_amdgcn_mfma_f32_32x32x16_bf16(ah[ks], bh[n], acc[n], 0, 0, 0);
    #pragma unroll
    for (int n = 0; n < NR; n++)
      acc[n] = __builtin_amdgcn_mfma_f32_32x32x16_bf16(ah[ks], bl[n], acc[n], 0, 0, 0);
    #pragma unroll
    for (int n = 0; n < NR; n++)
      acc[n] = __builtin_amdgcn_mfma_f32_32x32x16_bf16(al[ks], bh[n], acc[n], 0, 0, 0);
  }

  const float* bsrc = wn ? b2 : b1;
  _Float16* Y = wn ? Y2 : Y1;
  #pragma unroll
  for (int n = 0; n < NR; n++){
    float bias = bsrc[n * 32 + llane];
    #pragma unroll
    for (int reg = 0; reg < 16; reg++){
      int row = r0 + wm * 32 + (reg & 3) + 8 * (reg >> 2) + 4 * hlane;
      if (row < N)
        Y[(long)row * NOUT + n * 32 + llane] = (_Float16)(acc[n][reg] + bias);
    }
  }
}

// ---------------------------------------------------------------- packed-A MFMA dual GEMM (K=128)
// A comes prepacked in fragment order [kgroup][row][8k] (bf16 hi/lo), written by
// the previous layer's agg epilogue. Both operands are fully-coalesced 16B/lane
// streams; no LDS, no barriers, no in-kernel convert. fp16 outputs.
template<int NOUT>
__global__ __launch_bounds__(256) void gemm_dual_packed(
    const short* __restrict__ AH, const short* __restrict__ AL,
    const short* __restrict__ BH, const short* __restrict__ BL,
    const float* __restrict__ b1, const float* __restrict__ b2,
    _Float16* __restrict__ Y1, _Float16* __restrict__ Y2, int N)
{
  constexpr int BN     = 2 * NOUT;
  constexpr int KSTEPS = 8;                 // K = 128
  constexpr int NR     = NOUT / 32;

  int tid   = threadIdx.x;
  int lane  = tid & 63;
  int wid   = tid >> 6;
  int wm    = wid >> 1, wn = wid & 1;
  int llane = lane & 31, hlane = lane >> 5;
  int r0    = blockIdx.x * 64;
  int arow  = r0 + wm * 32 + llane;
  int ar    = arow < N ? arow : N - 1;      // clamp: extra rows never stored

  const s16x8* AHf = (const s16x8*)AH;
  const s16x8* ALf = (const s16x8*)AL;
  const s16x8* BHf = (const s16x8*)BH;
  const s16x8* BLf = (const s16x8*)BL;

  f32x16 acc[NR];
  #pragma unroll
  for (int n = 0; n < NR; n++)
    #pragma unroll
    for (int i = 0; i < 16; i++) acc[n][i] = 0.f;

  #pragma unroll
  for (int ks = 0; ks < KSTEPS; ks++){
    long fa = (long)(2 * ks + hlane) * N + ar;
    s16x8 ah = AHf[fa];
    s16x8 al = ALf[fa];
    long fb = (long)(2 * ks + hlane) * BN + wn * NOUT + llane;
    s16x8 bh[NR], bl[NR];
    #pragma unroll
    for (int n = 0; n < NR; n++){
      bh[n] = BHf[fb + n * 32];
      bl[n] = BLf[fb + n * 32];
    }
    #pragma unroll
    for (int n = 0; n < NR; n++)
      acc[n] = __builtin_amdgcn_mfma_f32_32x32x16_bf16(ah, bh[n], acc[n], 0, 0, 0);
    #pragma unroll
    for (int n = 0; n < NR; n++)
      acc[n] = __builtin_amdgcn_mfma_f32_32x32x16_bf16(ah, bl[n], acc[n], 0, 0, 0);
    #pragma unroll
    for (int n = 0; n < NR; n++)
      acc[n] = __builtin_amdgcn_mfma_f32_32x32x16_bf16(al, bh[n], acc[n], 0, 0, 0);
  }

  const float* bsrc = wn ? b2 : b1;
  _Float16* Y = wn ? Y2 : Y1;
  #pragma unroll
  for (int n = 0; n < NR; n++){
    float bias = bsrc[n * 32 + llane];
    #pragma unroll
    for (int reg = 0; reg < 16; reg++){
      int row = r0 + wm * 32 + (reg & 3) + 8 * (reg >> 2) + 4 * hlane;
      if (row < N)
        Y[(long)row * NOUT + n * 32 + llane] = (_Float16)(acc[n][reg] + bias);
    }
  }
}

// ---------------------------------------------------------------- fused edge softmax + aggregation
// One wave per dst node (grid-stride). R7: 8 channels per lane (f16x8 loads).
// C=16: LPH=2 lanes/head, LPE=16, ES=4, NP=2 -> B=8 (B kept at 8: tail waste
// ceil(deg/B) would jump 22%->43% at B=16 for deg~Poisson(16)).
// C=8: LPH=1 (lane == head, logit shuffle vanishes), LPE=8, ES=8, B=16.
// Per-edge wave-instructions ~12.5 -> ~8.5 (agg is VALU-issue-bound: R5 showed
// FETCH halved with dur unchanged; R6's inst cut gave -18%).
// NOTE (R1): loads stay unconditional+batched; no predication on tail.
template<int C>
__global__ __launch_bounds__(512) void agg_kernel(
    const _Float16* __restrict__ xl, const _Float16* __restrict__ xr,
    const int* __restrict__ base, const int* __restrict__ deg,
    const int2* __restrict__ csr_pack,
    const float* __restrict__ We, const float* __restrict__ att,
    const float* __restrict__ bias, float* __restrict__ hout,
    short* __restrict__ packH, short* __restrict__ packL,
    const float* __restrict__ Wlin, const float* __restrict__ blin,
    float* __restrict__ outF, int N, int do_elu)
{
  constexpr int HC  = 8 * C;
  constexpr int LPH = C / 8;       // lanes per head (2 for C=16, 1 for C=8)
  constexpr int LPE = 8 * LPH;     // lanes per edge (16 or 8)
  constexpr int ES  = 64 / LPE;    // edge slots per pass (4 or 8)
  constexpr int NP  = 2;           // passes per iteration
  constexpr int B   = ES * NP;     // edges per iteration (8 or 16)

  int lane = threadIdx.x & 63;
  int wv   = blockIdx.x * (blockDim.x >> 6) + (threadIdx.x >> 6);
  int nwv  = gridDim.x * (blockDim.x >> 6);
  int slot = lane / LPE;           // edge slot within pass
  int hl   = lane % LPE;           // position within edge
  int coff = hl * 8;               // channel offset (8 ch/lane)

  const float* attp = att + coff;
  const float* wep  = We  + coff;
  f16x2 a0 = { (_Float16)attp[0], (_Float16)attp[1] };
  f16x2 a1 = { (_Float16)attp[2], (_Float16)attp[3] };
  f16x2 a2 = { (_Float16)attp[4], (_Float16)attp[5] };
  f16x2 a3 = { (_Float16)attp[6], (_Float16)attp[7] };
  f16x2 w0 = { (_Float16)wep[0], (_Float16)wep[1] };
  f16x2 w1 = { (_Float16)wep[2], (_Float16)wep[3] };
  f16x2 w2 = { (_Float16)wep[4], (_Float16)wep[5] };
  f16x2 w3 = { (_Float16)wep[6], (_Float16)wep[7] };
  f16x2 sl2 = { (_Float16)NEG_SLOPE, (_Float16)NEG_SLOPE };

  float bv[8], wlv[8];
  #pragma unroll
  for (int i = 0; i < 8; i++){
    bv[i]  = bias[coff + i];
    wlv[i] = outF ? Wlin[coff + i] : 0.f;
  }

  for (int n = wv; n < N; n += nwv){
    f16x8 xr8 = *(const f16x8*)(xr + (long)n * HC + coff);
    f16x2 x0 = PAIR(xr8, 0), x1 = PAIR(xr8, 1), x2 = PAIR(xr8, 2), x3 = PAIR(xr8, 3);
    float acc[8];
    #pragma unroll
    for (int i = 0; i < 8; i++) acc[i] = 0.f;
    float lrun = 0.f;
    int s0 = base[n], end = s0 + deg[n];

    for (int s = s0; s < end; s += B){
      int2 pk[NP]; bool val[NP];
      #pragma unroll
      for (int t = 0; t < NP; t++){
        int idx = s + t * ES + slot;
        val[t] = idx < end;
        pk[t]  = csr_pack[val[t] ? idx : s0];
      }
      f16x8 rh[NP];
      #pragma unroll
      for (int t = 0; t < NP; t++)
        rh[t] = *(const f16x8*)(xl + (long)pk[t].x * HC + coff);
      #pragma unroll
      for (int t = 0; t < NP; t++){
        f16x2 ev = *(const f16x2*)&pk[t].y;       // broadcast half2
        f16x2 t0 = PAIR(rh[t], 0) + (ev * w0 + x0);
        f16x2 t1 = PAIR(rh[t], 1) + (ev * w1 + x1);
        f16x2 t2 = PAIR(rh[t], 2) + (ev * w2 + x2);
        f16x2 t3 = PAIR(rh[t], 3) + (ev * w3 + x3);
        f16x2 m0 = __builtin_elementwise_max(t0, t0 * sl2);
        f16x2 m1 = __builtin_elementwise_max(t1, t1 * sl2);
        f16x2 m2 = __builtin_elementwise_max(t2, t2 * sl2);
        f16x2 m3 = __builtin_elementwise_max(t3, t3 * sl2);
        float p = __builtin_amdgcn_fdot2(m0, a0,
                  __builtin_amdgcn_fdot2(m1, a1,
                  __builtin_amdgcn_fdot2(m2, a2,
                  __builtin_amdgcn_fdot2(m3, a3, 0.f, false), false), false), false);
        if constexpr (LPH > 1){
          #pragma unroll
          for (int o = 1; o < LPH; o <<= 1) p += __shfl_xor(p, o);
        }
        float pe = val[t] ? __expf(p) : 0.f;
        lrun += pe;
        #pragma unroll
        for (int i = 0; i < 8; i++) acc[i] += pe * (float)rh[t][i];
      }
    }
    // reduce over edge slots
    #pragma unroll
    for (int o = LPE; o < 64; o <<= 1){
      lrun += __shfl_xor(lrun, o);
      #pragma unroll
      for (int i = 0; i < 8; i++) acc[i] += __shfl_xor(acc[i], o);
    }
    float inv = 1.f / (lrun + 1e-16f);
    float o8[8];
    #pragma unroll
    for (int i = 0; i < 8; i++) o8[i] = acc[i] * inv + bv[i];
    if (do_elu){
      #pragma unroll
      for (int i = 0; i < 8; i++)
        o8[i] = o8[i] > 0.f ? o8[i] : (__expf(o8[i]) - 1.f);
    }
    if (outF){
      // fused final linear: out[n] = sum_c o_c * Wlin_c + blin
      float v = 0.f;
      #pragma unroll
      for (int i = 0; i < 8; i++) v += o8[i] * wlv[i];
      #pragma unroll
      for (int o = 1; o < LPE; o <<= 1) v += __shfl_xor(v, o);
      if (lane == 0) outF[n] = v + blin[0];
    } else if (packH){
      // write MFMA A-fragments: lane hl's 8 channels are exactly kgroup hl
      // -> one s16x8 (16B) store per buffer at shorts idx (hl*N + n)*8
      if (slot == 0){
        s16x8 hv, lv;
        #pragma unroll
        for (int i = 0; i < 8; i++){
          unsigned short h = f2bf(o8[i]);
          hv[i] = (short)h;
          lv[i] = (short)f2bf(o8[i] - bf2f(h));
        }
        long idx = ((long)hl * N + n) * 8;
        *(s16x8*)(packH + idx) = hv;
        *(s16x8*)(packL + idx) = lv;
      }
    } else {
      if (slot == 0){
        *(float4*)(hout + (long)n * HC + coff)     = make_float4(o8[0], o8[1], o8[2], o8[3]);
        *(float4*)(hout + (long)n * HC + coff + 4) = make_float4(o8[4], o8[5], o8[6], o8[7]);
      }
    }
  }
}

// ----------------------------------------------------------------
extern "C" void kernel_launch(void* const* d_in, const int* in_sizes, int n_in,
                              void* d_out, int out_size, void* d_ws, size_t ws_size,
                              hipStream_t stream)
{
  const float* x  = (const float*)d_in[0];
  const float* ea = (const float*)d_in[1];
  const int*   ei = (const int*)d_in[2];
  const int N = in_sizes[0] / 15;
  const int E = in_sizes[1];

  const float* P[28];
  for (int i = 0; i < 28; i++) P[i] = (const float*)d_in[3 + i];
  const float* Wlin = (const float*)d_in[31];
  const float* blin = (const float*)d_in[32];

  size_t off = 0;
  auto carve = [&](size_t bytes) -> char* {
    char* p = (char*)d_ws + off;
    off = (off + bytes + 255) & ~(size_t)255;
    return p;
  };
  int*   meta     = (int*)  carve(sizeof(int)  * (size_t)(3 * N + 64));
  int*   deg      = meta;                // [N] zeroed
  int*   pos      = meta + N;            // [N] zeroed
  int*   base     = meta + 2 * N;        // [N]
  int*   counter  = meta + 3 * N;        // [1] zeroed
  int2*  csr_pack = (int2*) carve(sizeof(int2) * (size_t)E);
  _Float16* xl    = (_Float16*)carve(sizeof(_Float16) * (size_t)N * 128);
  _Float16* xr    = (_Float16*)carve(sizeof(_Float16) * (size_t)N * 128);
  short* pak_h    = (short*)carve(sizeof(short) * (size_t)N * 128);
  short* pak_l    = (short*)carve(sizeof(short) * (size_t)N * 128);
  // prepacked bf16 hi/lo weights, MFMA B-fragment order
  short* ph1 = (short*)carve(sizeof(short) * 4096);
  short* pl1 = (short*)carve(sizeof(short) * 4096);
  short* ph2 = (short*)carve(sizeof(short) * 32768);
  short* pl2 = (short*)carve(sizeof(short) * 32768);
  short* ph3 = (short*)carve(sizeof(short) * 32768);
  short* pl3 = (short*)carve(sizeof(short) * 32768);
  short* ph4 = (short*)carve(sizeof(short) * 16384);
  short* pl4 = (short*)carve(sizeof(short) * 16384);

  hipMemsetAsync(deg,     0, sizeof(int) * (size_t)(2 * N), stream);
  hipMemsetAsync(counter, 0, sizeof(int), stream);

  int eb = (E + 255) / 256;
  int nb = (N + 255) / 256;
  deg_count_kernel  <<<eb, 256, 0, stream>>>(ei + E, deg, E);
  base_assign_kernel<<<nb, 256, 0, stream>>>(deg, base, counter, N);
  fill_kernel       <<<eb, 256, 0, stream>>>(ei, ea, base, pos, csr_pack, E);
  prep_w_kernel     <<<42, 256, 0, stream>>>(P[0],  P[2],  ph1, pl1,
                                             P[7],  P[9],  ph2, pl2,
                                             P[14], P[16], ph3, pl3,
                                             P[21], P[23], ph4, pl4);

  int gm    = (N + 63) / 64;  // 64-row MFMA tiles
  int agrid = 2048;           // agg: grid-stride, 8 waves/block

  // layer 1: din=15, H*C=128, ELU; agg writes packed A for gemm2
  gemm_dual_mfma<128, 15><<<gm, 256, 0, stream>>>(x, ph1, pl1, P[1], P[3], xl, xr, N);
  agg_kernel<16><<<agrid, 512, 0, stream>>>(xl, xr, base, deg, csr_pack, P[4], P[5], P[6],
                                            nullptr, pak_h, pak_l,
                                            nullptr, nullptr, nullptr, N, 1);
  // layer 2: din=128, ELU; agg writes packed A for gemm3
  gemm_dual_packed<128><<<gm, 256, 0, stream>>>(pak_h, pak_l, ph2, pl2, P[8], P[10], xl, xr, N);
  agg_kernel<16><<<agrid, 512, 0, stream>>>(xl, xr, base, deg, csr_pack, P[11], P[12], P[13],
                                            nullptr, pak_h, pak_l,
                                            nullptr, nullptr, nullptr, N, 1);
  // layer 3: din=128, ELU; agg writes packed A for gemm4
  gemm_dual_packed<128><<<gm, 256, 0, stream>>>(pak_h, pak_l, ph3, pl3, P[15], P[17], xl, xr, N);
  agg_kernel<16><<<agrid, 512, 0, stream>>>(xl, xr, base, deg, csr_pack, P[18], P[19], P[20],
                                            nullptr, pak_h, pak_l,
                                            nullptr, nullptr, nullptr, N, 1);
  // layer 4: din=128, H*C=64, no ELU + fused final linear 64->1
  gemm_dual_packed<64><<<gm, 256, 0, stream>>>(pak_h, pak_l, ph4, pl4, P[22], P[24], xl, xr, N);
  agg_kernel<8><<<agrid, 512, 0, stream>>>(xl, xr, base, deg, csr_pack, P[25], P[26], P[27],
                                           nullptr, nullptr, nullptr,
                                           Wlin, blin, (float*)d_out, N, 0);
}

// Round 8
// 533.405 us; speedup vs baseline: 1.0072x; 1.0072x over previous
//
#include <hip/hip_runtime.h>
#include <math.h>

#define NEG_SLOPE 0.2f

typedef short s16x4 __attribute__((ext_vector_type(4)));
typedef short s16x8 __attribute__((ext_vector_type(8)));
typedef float f32x16 __attribute__((ext_vector_type(16)));
typedef _Float16 f16x2 __attribute__((ext_vector_type(2)));
typedef _Float16 f16x4 __attribute__((ext_vector_type(4)));
typedef _Float16 f16x8 __attribute__((ext_vector_type(8)));

#define PAIR(v,i) __builtin_shufflevector(v, v, 2*(i), 2*(i)+1)

// float -> bf16 (round-to-nearest-even), and back
__device__ __forceinline__ unsigned short f2bf(float x){
  unsigned int u = __float_as_uint(x);
  unsigned int r = u + 0x7FFFu + ((u >> 16) & 1u);
  return (unsigned short)(r >> 16);
}
__device__ __forceinline__ float bf2f(unsigned short h){
  return __uint_as_float(((unsigned int)h) << 16);
}

// ---------------------------------------------------------------- CSR build
__global__ void deg_count_kernel(const int* __restrict__ dst, int* __restrict__ deg, int E){
  int e = blockIdx.x * blockDim.x + threadIdx.x;
  if (e < E) atomicAdd(&deg[dst[e]], 1);
}

// block-scan prefix allocation (196 atomics total) instead of 50k
// same-address atomics (serialized at L2).
__global__ __launch_bounds__(256) void base_assign_kernel(
    const int* __restrict__ deg, int* __restrict__ base,
    int* __restrict__ counter, int N){
  __shared__ int wsum[4];
  __shared__ int bbase;
  int n = blockIdx.x * 256 + threadIdx.x;
  int d = (n < N) ? deg[n] : 0;
  int lane = threadIdx.x & 63;
  int wid  = threadIdx.x >> 6;
  int scan = d;
  #pragma unroll
  for (int o = 1; o < 64; o <<= 1){
    int t = __shfl_up(scan, o);
    if (lane >= o) scan += t;
  }
  if (lane == 63) wsum[wid] = scan;
  __syncthreads();
  if (threadIdx.x == 0){
    int tot = 0;
    #pragma unroll
    for (int i = 0; i < 4; i++){ int w = wsum[i]; wsum[i] = tot; tot += w; }
    bbase = atomicAdd(counter, tot);
  }
  __syncthreads();
  if (n < N) base[n] = bbase + wsum[wid] + scan - d;
}

// ea stored as broadcast half2 bits (h | h<<16) -- the agg reads it as
// f16x2 with zero per-edge conversion cost.
__global__ void fill_kernel(const int* __restrict__ ei, const float* __restrict__ ea,
                            const int* __restrict__ base, int* __restrict__ pos,
                            int2* __restrict__ csr_pack, int E){
  int e = blockIdx.x * blockDim.x + threadIdx.x;
  if (e >= E) return;
  int s = ei[e], d = ei[E + e];
  int p = atomicAdd(&pos[d], 1);
  _Float16 h = (_Float16)ea[e];
  unsigned int hb = (unsigned int)*(unsigned short*)&h;
  csr_pack[base[d] + p] = make_int2(s, (int)(hb | (hb << 16)));
}

// ---------------------------------------------------------------- weight prep
// Pack W1|W2 (each [K][NOUT] fp32 row-major) into bf16 hi/lo arrays laid out as
// [kgroup][col(2*NOUT)][8 k-elems] -- exactly the MFMA B-fragment order, so the
// GEMM reads B fragments as fully-coalesced 16B-per-lane global loads.
__device__ __forceinline__ void pack_pair(const float* __restrict__ W1,
                                          const float* __restrict__ W2,
                                          short* __restrict__ H, short* __restrict__ L,
                                          int id, int K, int NOUT){
  int BN = 2 * NOUT;
  int kg = id / BN, cb = id - kg * BN;
  const float* W = (cb < NOUT) ? W1 : W2;
  int c = (cb < NOUT) ? cb : cb - NOUT;
  s16x8 hv, lv;
  #pragma unroll
  for (int e = 0; e < 8; e++){
    int k = kg * 8 + e;
    float v = (k < K) ? W[(long)k * NOUT + c] : 0.f;
    unsigned short h = f2bf(v);
    hv[e] = (short)h;
    lv[e] = (short)f2bf(v - bf2f(h));
  }
  *(s16x8*)&H[(long)id * 8] = hv;
  *(s16x8*)&L[(long)id * 8] = lv;
}

__global__ void prep_w_kernel(const float* Wl1, const float* Wr1, short* H1, short* L1,
                              const float* Wl2, const float* Wr2, short* H2, short* L2,
                              const float* Wl3, const float* Wr3, short* H3, short* L3,
                              const float* Wl4, const float* Wr4, short* H4, short* L4){
  int id = blockIdx.x * blockDim.x + threadIdx.x;
  if (id < 512)  { pack_pair(Wl1, Wr1, H1, L1, id, 15, 128); return; }   // KG=2,  BN=256
  id -= 512;
  if (id < 4096) { pack_pair(Wl2, Wr2, H2, L2, id, 128, 128); return; }  // KG=16, BN=256
  id -= 4096;
  if (id < 4096) { pack_pair(Wl3, Wr3, H3, L3, id, 128, 128); return; }
  id -= 4096;
  if (id < 2048) { pack_pair(Wl4, Wr4, H4, L4, id, 128, 64); return; }   // KG=16, BN=128
}

// ---------------------------------------------------------------- MFMA dual GEMM (layer 1, K=15)
// A gathered+converted in-kernel (cheap at K=15: 1 kstep). Outputs fp16:
// xl/xr are only consumed by the agg (attention values); precision path to the
// next gemm flows through the agg's bf16 hi/lo pack, not these.
// Fragment layouts (gfx950 v_mfma_f32_32x32x16_bf16):
//   A: row = lane&31, k = 8*(lane>>5)+e     B: col = lane&31, k = 8*(lane>>5)+e
//   D: col = lane&31, row = (reg&3) + 8*(reg>>2) + 4*(lane>>5)
template<int NOUT, int K>
__global__ __launch_bounds__(256) void gemm_dual_mfma(
    const float* __restrict__ X,
    const short* __restrict__ BH, const short* __restrict__ BL,
    const float* __restrict__ b1, const float* __restrict__ b2,
    _Float16* __restrict__ Y1, _Float16* __restrict__ Y2, int N)
{
  constexpr int BN     = 2 * NOUT;
  constexpr int KSTEPS = (K + 15) / 16;     // one 32x32x16 MFMA step each
  constexpr int NR     = NOUT / 32;         // col fragments per wave (4 or 2)

  int tid   = threadIdx.x;
  int lane  = tid & 63;
  int wid   = tid >> 6;
  int wm    = wid >> 1, wn = wid & 1;       // block = 64 rows x (Y1|Y2)
  int llane = lane & 31, hlane = lane >> 5;
  int r0    = blockIdx.x * 64;

  // ---- A: load this lane's row (half-K per lane-half), convert hi/lo once
  int arow  = r0 + wm * 32 + llane;
  bool rv   = arow < N;
  const float* px = X + (long)arow * K;

  s16x8 ah[KSTEPS], al[KSTEPS];
  #pragma unroll
  for (int ks = 0; ks < KSTEPS; ks++){
    int kg = (2 * ks + hlane) * 8;
    float v[8];
    if constexpr (K % 8 == 0){
      float4 p0 = {0.f,0.f,0.f,0.f}, p1 = {0.f,0.f,0.f,0.f};
      if (rv){
        p0 = *(const float4*)(px + kg);
        p1 = *(const float4*)(px + kg + 4);
      }
      v[0]=p0.x; v[1]=p0.y; v[2]=p0.z; v[3]=p0.w;
      v[4]=p1.x; v[5]=p1.y; v[6]=p1.z; v[7]=p1.w;
    } else {
      #pragma unroll
      for (int e = 0; e < 8; e++)
        v[e] = (rv && kg + e < K) ? px[kg + e] : 0.f;
    }
    #pragma unroll
    for (int e = 0; e < 8; e++){
      unsigned short h = f2bf(v[e]);
      ah[ks][e] = (short)h;
      al[ks][e] = (short)f2bf(v[e] - bf2f(h));
    }
  }

  f32x16 acc[NR];
  #pragma unroll
  for (int n = 0; n < NR; n++)
    #pragma unroll
    for (int i = 0; i < 16; i++) acc[n][i] = 0.f;

  const s16x8* BHf = (const s16x8*)BH;
  const s16x8* BLf = (const s16x8*)BL;
  #pragma unroll
  for (int ks = 0; ks < KSTEPS; ks++){
    long fb = (long)(2 * ks + hlane) * BN + wn * NOUT + llane;
    s16x8 bh[NR], bl[NR];
    #pragma unroll
    for (int n = 0; n < NR; n++){
      bh[n] = BHf[fb + n * 32];
      bl[n] = BLf[fb + n * 32];
    }
    #pragma unroll
    for (int n = 0; n < NR; n++)
      acc[n] = __builtin_amdgcn_mfma_f32_32x32x16_bf16(ah[ks], bh[n], acc[n], 0, 0, 0);
    #pragma unroll
    for (int n = 0; n < NR; n++)
      acc[n] = __builtin_amdgcn_mfma_f32_32x32x16_bf16(ah[ks], bl[n], acc[n], 0, 0, 0);
    #pragma unroll
    for (int n = 0; n < NR; n++)
      acc[n] = __builtin_amdgcn_mfma_f32_32x32x16_bf16(al[ks], bh[n], acc[n], 0, 0, 0);
  }

  const float* bsrc = wn ? b2 : b1;
  _Float16* Y = wn ? Y2 : Y1;
  #pragma unroll
  for (int n = 0; n < NR; n++){
    float bias = bsrc[n * 32 + llane];
    #pragma unroll
    for (int reg = 0; reg < 16; reg++){
      int row = r0 + wm * 32 + (reg & 3) + 8 * (reg >> 2) + 4 * hlane;
      if (row < N)
        Y[(long)row * NOUT + n * 32 + llane] = (_Float16)(acc[n][reg] + bias);
    }
  }
}

// ---------------------------------------------------------------- packed-A MFMA dual GEMM (K=128)
// A comes prepacked in fragment order [kgroup][row][8k] (bf16 hi/lo), written by
// the previous layer's agg epilogue. Both operands are fully-coalesced 16B/lane
// streams; no LDS, no barriers, no in-kernel convert. fp16 outputs.
template<int NOUT>
__global__ __launch_bounds__(256) void gemm_dual_packed(
    const short* __restrict__ AH, const short* __restrict__ AL,
    const short* __restrict__ BH, const short* __restrict__ BL,
    const float* __restrict__ b1, const float* __restrict__ b2,
    _Float16* __restrict__ Y1, _Float16* __restrict__ Y2, int N)
{
  constexpr int BN     = 2 * NOUT;
  constexpr int KSTEPS = 8;                 // K = 128
  constexpr int NR     = NOUT / 32;

  int tid   = threadIdx.x;
  int lane  = tid & 63;
  int wid   = tid >> 6;
  int wm    = wid >> 1, wn = wid & 1;
  int llane = lane & 31, hlane = lane >> 5;
  int r0    = blockIdx.x * 64;
  int arow  = r0 + wm * 32 + llane;
  int ar    = arow < N ? arow : N - 1;      // clamp: extra rows never stored

  const s16x8* AHf = (const s16x8*)AH;
  const s16x8* ALf = (const s16x8*)AL;
  const s16x8* BHf = (const s16x8*)BH;
  const s16x8* BLf = (const s16x8*)BL;

  f32x16 acc[NR];
  #pragma unroll
  for (int n = 0; n < NR; n++)
    #pragma unroll
    for (int i = 0; i < 16; i++) acc[n][i] = 0.f;

  #pragma unroll
  for (int ks = 0; ks < KSTEPS; ks++){
    long fa = (long)(2 * ks + hlane) * N + ar;
    s16x8 ah = AHf[fa];
    s16x8 al = ALf[fa];
    long fb = (long)(2 * ks + hlane) * BN + wn * NOUT + llane;
    s16x8 bh[NR], bl[NR];
    #pragma unroll
    for (int n = 0; n < NR; n++){
      bh[n] = BHf[fb + n * 32];
      bl[n] = BLf[fb + n * 32];
    }
    #pragma unroll
    for (int n = 0; n < NR; n++)
      acc[n] = __builtin_amdgcn_mfma_f32_32x32x16_bf16(ah, bh[n], acc[n], 0, 0, 0);
    #pragma unroll
    for (int n = 0; n < NR; n++)
      acc[n] = __builtin_amdgcn_mfma_f32_32x32x16_bf16(ah, bl[n], acc[n], 0, 0, 0);
    #pragma unroll
    for (int n = 0; n < NR; n++)
      acc[n] = __builtin_amdgcn_mfma_f32_32x32x16_bf16(al, bh[n], acc[n], 0, 0, 0);
  }

  const float* bsrc = wn ? b2 : b1;
  _Float16* Y = wn ? Y2 : Y1;
  #pragma unroll
  for (int n = 0; n < NR; n++){
    float bias = bsrc[n * 32 + llane];
    #pragma unroll
    for (int reg = 0; reg < 16; reg++){
      int row = r0 + wm * 32 + (reg & 3) + 8 * (reg >> 2) + 4 * hlane;
      if (row < N)
        Y[(long)row * NOUT + n * 32 + llane] = (_Float16)(acc[n][reg] + bias);
    }
  }
}

// ---------------------------------------------------------------- fused edge softmax + aggregation
// One wave per dst node (grid-stride). 8 channels per lane (f16x8 loads).
// R8: NP back to 4 for C=16 (R7 post-mortem: NP=2 halved lane-level MLP
// 8->4 outstanding loads -> latency-bound, 58->71us despite fewer insts).
// B=16 tail waste (~1.46x at deg~Poisson(16)) is cheaper than lost MLP:
// per-real-edge ~8.5x1.46=12.4 inst vs R6's 12.5x1.25=15.6.
// C=8: LPE=8, ES=8, NP=3 -> B=24 (NP=4 would give B=32, 2.0x tail).
// NOTE (R1/R7): loads stay unconditional+batched, >=6 outstanding per lane.
template<int C, int NP>
__global__ __launch_bounds__(512) void agg_kernel(
    const _Float16* __restrict__ xl, const _Float16* __restrict__ xr,
    const int* __restrict__ base, const int* __restrict__ deg,
    const int2* __restrict__ csr_pack,
    const float* __restrict__ We, const float* __restrict__ att,
    const float* __restrict__ bias, float* __restrict__ hout,
    short* __restrict__ packH, short* __restrict__ packL,
    const float* __restrict__ Wlin, const float* __restrict__ blin,
    float* __restrict__ outF, int N, int do_elu)
{
  constexpr int HC  = 8 * C;
  constexpr int LPH = C / 8;       // lanes per head (2 for C=16, 1 for C=8)
  constexpr int LPE = 8 * LPH;     // lanes per edge (16 or 8)
  constexpr int ES  = 64 / LPE;    // edge slots per pass (4 or 8)
  constexpr int B   = ES * NP;     // edges per iteration

  int lane = threadIdx.x & 63;
  int wv   = blockIdx.x * (blockDim.x >> 6) + (threadIdx.x >> 6);
  int nwv  = gridDim.x * (blockDim.x >> 6);
  int slot = lane / LPE;           // edge slot within pass
  int hl   = lane % LPE;           // position within edge
  int coff = hl * 8;               // channel offset (8 ch/lane)

  const float* attp = att + coff;
  const float* wep  = We  + coff;
  f16x2 a0 = { (_Float16)attp[0], (_Float16)attp[1] };
  f16x2 a1 = { (_Float16)attp[2], (_Float16)attp[3] };
  f16x2 a2 = { (_Float16)attp[4], (_Float16)attp[5] };
  f16x2 a3 = { (_Float16)attp[6], (_Float16)attp[7] };
  f16x2 w0 = { (_Float16)wep[0], (_Float16)wep[1] };
  f16x2 w1 = { (_Float16)wep[2], (_Float16)wep[3] };
  f16x2 w2 = { (_Float16)wep[4], (_Float16)wep[5] };
  f16x2 w3 = { (_Float16)wep[6], (_Float16)wep[7] };
  f16x2 sl2 = { (_Float16)NEG_SLOPE, (_Float16)NEG_SLOPE };

  float bv[8], wlv[8];
  #pragma unroll
  for (int i = 0; i < 8; i++){
    bv[i]  = bias[coff + i];
    wlv[i] = outF ? Wlin[coff + i] : 0.f;
  }

  for (int n = wv; n < N; n += nwv){
    f16x8 xr8 = *(const f16x8*)(xr + (long)n * HC + coff);
    f16x2 x0 = PAIR(xr8, 0), x1 = PAIR(xr8, 1), x2 = PAIR(xr8, 2), x3 = PAIR(xr8, 3);
    float acc[8];
    #pragma unroll
    for (int i = 0; i < 8; i++) acc[i] = 0.f;
    float lrun = 0.f;
    int s0 = base[n], end = s0 + deg[n];

    for (int s = s0; s < end; s += B){
      int2 pk[NP]; bool val[NP];
      #pragma unroll
      for (int t = 0; t < NP; t++){
        int idx = s + t * ES + slot;
        val[t] = idx < end;
        pk[t]  = csr_pack[val[t] ? idx : s0];
      }
      f16x8 rh[NP];
      #pragma unroll
      for (int t = 0; t < NP; t++)
        rh[t] = *(const f16x8*)(xl + (long)pk[t].x * HC + coff);
      #pragma unroll
      for (int t = 0; t < NP; t++){
        f16x2 ev = *(const f16x2*)&pk[t].y;       // broadcast half2
        f16x2 t0 = PAIR(rh[t], 0) + (ev * w0 + x0);
        f16x2 t1 = PAIR(rh[t], 1) + (ev * w1 + x1);
        f16x2 t2 = PAIR(rh[t], 2) + (ev * w2 + x2);
        f16x2 t3 = PAIR(rh[t], 3) + (ev * w3 + x3);
        f16x2 m0 = __builtin_elementwise_max(t0, t0 * sl2);
        f16x2 m1 = __builtin_elementwise_max(t1, t1 * sl2);
        f16x2 m2 = __builtin_elementwise_max(t2, t2 * sl2);
        f16x2 m3 = __builtin_elementwise_max(t3, t3 * sl2);
        float p = __builtin_amdgcn_fdot2(m0, a0,
                  __builtin_amdgcn_fdot2(m1, a1,
                  __builtin_amdgcn_fdot2(m2, a2,
                  __builtin_amdgcn_fdot2(m3, a3, 0.f, false), false), false), false);
        if constexpr (LPH > 1){
          #pragma unroll
          for (int o = 1; o < LPH; o <<= 1) p += __shfl_xor(p, o);
        }
        float pe = val[t] ? __expf(p) : 0.f;
        lrun += pe;
        #pragma unroll
        for (int i = 0; i < 8; i++) acc[i] += pe * (float)rh[t][i];
      }
    }
    // reduce over edge slots
    #pragma unroll
    for (int o = LPE; o < 64; o <<= 1){
      lrun += __shfl_xor(lrun, o);
      #pragma unroll
      for (int i = 0; i < 8; i++) acc[i] += __shfl_xor(acc[i], o);
    }
    float inv = 1.f / (lrun + 1e-16f);
    float o8[8];
    #pragma unroll
    for (int i = 0; i < 8; i++) o8[i] = acc[i] * inv + bv[i];
    if (do_elu){
      #pragma unroll
      for (int i = 0; i < 8; i++)
        o8[i] = o8[i] > 0.f ? o8[i] : (__expf(o8[i]) - 1.f);
    }
    if (outF){
      // fused final linear: out[n] = sum_c o_c * Wlin_c + blin
      float v = 0.f;
      #pragma unroll
      for (int i = 0; i < 8; i++) v += o8[i] * wlv[i];
      #pragma unroll
      for (int o = 1; o < LPE; o <<= 1) v += __shfl_xor(v, o);
      if (lane == 0) outF[n] = v + blin[0];
    } else if (packH){
      // write MFMA A-fragments: lane hl's 8 channels are exactly kgroup hl
      // -> one s16x8 (16B) store per buffer at shorts idx (hl*N + n)*8
      if (slot == 0){
        s16x8 hv, lv;
        #pragma unroll
        for (int i = 0; i < 8; i++){
          unsigned short h = f2bf(o8[i]);
          hv[i] = (short)h;
          lv[i] = (short)f2bf(o8[i] - bf2f(h));
        }
        long idx = ((long)hl * N + n) * 8;
        *(s16x8*)(packH + idx) = hv;
        *(s16x8*)(packL + idx) = lv;
      }
    } else {
      if (slot == 0){
        *(float4*)(hout + (long)n * HC + coff)     = make_float4(o8[0], o8[1], o8[2], o8[3]);
        *(float4*)(hout + (long)n * HC + coff + 4) = make_float4(o8[4], o8[5], o8[6], o8[7]);
      }
    }
  }
}

// ----------------------------------------------------------------
extern "C" void kernel_launch(void* const* d_in, const int* in_sizes, int n_in,
                              void* d_out, int out_size, void* d_ws, size_t ws_size,
                              hipStream_t stream)
{
  const float* x  = (const float*)d_in[0];
  const float* ea = (const float*)d_in[1];
  const int*   ei = (const int*)d_in[2];
  const int N = in_sizes[0] / 15;
  const int E = in_sizes[1];

  const float* P[28];
  for (int i = 0; i < 28; i++) P[i] = (const float*)d_in[3 + i];
  const float* Wlin = (const float*)d_in[31];
  const float* blin = (const float*)d_in[32];

  size_t off = 0;
  auto carve = [&](size_t bytes) -> char* {
    char* p = (char*)d_ws + off;
    off = (off + bytes + 255) & ~(size_t)255;
    return p;
  };
  int*   meta     = (int*)  carve(sizeof(int)  * (size_t)(3 * N + 64));
  int*   deg      = meta;                // [N] zeroed
  int*   pos      = meta + N;            // [N] zeroed
  int*   base     = meta + 2 * N;        // [N]
  int*   counter  = meta + 3 * N;        // [1] zeroed
  int2*  csr_pack = (int2*) carve(sizeof(int2) * (size_t)E);
  _Float16* xl    = (_Float16*)carve(sizeof(_Float16) * (size_t)N * 128);
  _Float16* xr    = (_Float16*)carve(sizeof(_Float16) * (size_t)N * 128);
  short* pak_h    = (short*)carve(sizeof(short) * (size_t)N * 128);
  short* pak_l    = (short*)carve(sizeof(short) * (size_t)N * 128);
  // prepacked bf16 hi/lo weights, MFMA B-fragment order
  short* ph1 = (short*)carve(sizeof(short) * 4096);
  short* pl1 = (short*)carve(sizeof(short) * 4096);
  short* ph2 = (short*)carve(sizeof(short) * 32768);
  short* pl2 = (short*)carve(sizeof(short) * 32768);
  short* ph3 = (short*)carve(sizeof(short) * 32768);
  short* pl3 = (short*)carve(sizeof(short) * 32768);
  short* ph4 = (short*)carve(sizeof(short) * 16384);
  short* pl4 = (short*)carve(sizeof(short) * 16384);

  hipMemsetAsync(deg,     0, sizeof(int) * (size_t)(2 * N), stream);
  hipMemsetAsync(counter, 0, sizeof(int), stream);

  int eb = (E + 255) / 256;
  int nb = (N + 255) / 256;
  deg_count_kernel  <<<eb, 256, 0, stream>>>(ei + E, deg, E);
  base_assign_kernel<<<nb, 256, 0, stream>>>(deg, base, counter, N);
  fill_kernel       <<<eb, 256, 0, stream>>>(ei, ea, base, pos, csr_pack, E);
  prep_w_kernel     <<<42, 256, 0, stream>>>(P[0],  P[2],  ph1, pl1,
                                             P[7],  P[9],  ph2, pl2,
                                             P[14], P[16], ph3, pl3,
                                             P[21], P[23], ph4, pl4);

  int gm    = (N + 63) / 64;  // 64-row MFMA tiles
  int agrid = 2048;           // agg: grid-stride, 8 waves/block

  // layer 1: din=15, H*C=128, ELU; agg writes packed A for gemm2
  gemm_dual_mfma<128, 15><<<gm, 256, 0, stream>>>(x, ph1, pl1, P[1], P[3], xl, xr, N);
  agg_kernel<16,4><<<agrid, 512, 0, stream>>>(xl, xr, base, deg, csr_pack, P[4], P[5], P[6],
                                              nullptr, pak_h, pak_l,
                                              nullptr, nullptr, nullptr, N, 1);
  // layer 2: din=128, ELU; agg writes packed A for gemm3
  gemm_dual_packed<128><<<gm, 256, 0, stream>>>(pak_h, pak_l, ph2, pl2, P[8], P[10], xl, xr, N);
  agg_kernel<16,4><<<agrid, 512, 0, stream>>>(xl, xr, base, deg, csr_pack, P[11], P[12], P[13],
                                              nullptr, pak_h, pak_l,
                                              nullptr, nullptr, nullptr, N, 1);
  // layer 3: din=128, ELU; agg writes packed A for gemm4
  gemm_dual_packed<128><<<gm, 256, 0, stream>>>(pak_h, pak_l, ph3, pl3, P[15], P[17], xl, xr, N);
  agg_kernel<16,4><<<agrid, 512, 0, stream>>>(xl, xr, base, deg, csr_pack, P[18], P[19], P[20],
                                              nullptr, pak_h, pak_l,
                                              nullptr, nullptr, nullptr, N, 1);
  // layer 4: din=128, H*C=64, no ELU + fused final linear 64->1
  gemm_dual_packed<64><<<gm, 256, 0, stream>>>(pak_h, pak_l, ph4, pl4, P[22], P[24], xl, xr, N);
  agg_kernel<8,3><<<agrid, 512, 0, stream>>>(xl, xr, base, deg, csr_pack, P[25], P[26], P[27],
                                             nullptr, nullptr, nullptr,
                                             Wlin, blin, (float*)d_out, N, 0);
}

// Round 9
// 466.591 us; speedup vs baseline: 1.1515x; 1.1432x over previous
//
#include <hip/hip_runtime.h>
#include <math.h>

#define NEG_SLOPE 0.2f

typedef short s16x4 __attribute__((ext_vector_type(4)));
typedef short s16x8 __attribute__((ext_vector_type(8)));
typedef float f32x16 __attribute__((ext_vector_type(16)));
typedef _Float16 f16x2 __attribute__((ext_vector_type(2)));
typedef _Float16 f16x4 __attribute__((ext_vector_type(4)));

// float -> bf16 (round-to-nearest-even), and back
__device__ __forceinline__ unsigned short f2bf(float x){
  unsigned int u = __float_as_uint(x);
  unsigned int r = u + 0x7FFFu + ((u >> 16) & 1u);
  return (unsigned short)(r >> 16);
}
__device__ __forceinline__ float bf2f(unsigned short h){
  return __uint_as_float(((unsigned int)h) << 16);
}

// ---------------------------------------------------------------- weight prep body
// Pack W1|W2 (each [K][NOUT] fp32 row-major) into bf16 hi/lo arrays laid out as
// [kgroup][col(2*NOUT)][8 k-elems] -- exactly the MFMA B-fragment order.
__device__ __forceinline__ void pack_pair(const float* __restrict__ W1,
                                          const float* __restrict__ W2,
                                          short* __restrict__ H, short* __restrict__ L,
                                          int id, int K, int NOUT){
  int BN = 2 * NOUT;
  int kg = id / BN, cb = id - kg * BN;
  const float* W = (cb < NOUT) ? W1 : W2;
  int c = (cb < NOUT) ? cb : cb - NOUT;
  s16x8 hv, lv;
  #pragma unroll
  for (int e = 0; e < 8; e++){
    int k = kg * 8 + e;
    float v = (k < K) ? W[(long)k * NOUT + c] : 0.f;
    unsigned short h = f2bf(v);
    hv[e] = (short)h;
    lv[e] = (short)f2bf(v - bf2f(h));
  }
  *(s16x8*)&H[(long)id * 8] = hv;
  *(s16x8*)&L[(long)id * 8] = lv;
}

// ---------------------------------------------------------------- fused: deg_count || prep_w
// (R9: dispatch-count reduction -- independent work, union grid. deg blocks
// [0,eb), prep blocks [eb, eb+42).)
__global__ __launch_bounds__(256) void deg_prep_kernel(
    const int* __restrict__ dst, int* __restrict__ deg, int E, int eb,
    const float* Wl1, const float* Wr1, short* H1, short* L1,
    const float* Wl2, const float* Wr2, short* H2, short* L2,
    const float* Wl3, const float* Wr3, short* H3, short* L3,
    const float* Wl4, const float* Wr4, short* H4, short* L4)
{
  int bid = blockIdx.x;
  if (bid < eb){
    int e = bid * 256 + threadIdx.x;
    if (e < E) atomicAdd(&deg[dst[e]], 1);
    return;
  }
  int id = (bid - eb) * 256 + threadIdx.x;
  if (id < 512)  { pack_pair(Wl1, Wr1, H1, L1, id, 15, 128); return; }   // KG=2,  BN=256
  id -= 512;
  if (id < 4096) { pack_pair(Wl2, Wr2, H2, L2, id, 128, 128); return; }  // KG=16, BN=256
  id -= 4096;
  if (id < 4096) { pack_pair(Wl3, Wr3, H3, L3, id, 128, 128); return; }
  id -= 4096;
  if (id < 2048) { pack_pair(Wl4, Wr4, H4, L4, id, 128, 64); return; }   // KG=16, BN=128
}

// ---------------------------------------------------------------- gemm1 body (K=15)
// A gathered+converted in-kernel (cheap at K=15: 1 kstep). fp16 outputs.
// Fragment layouts (gfx950 v_mfma_f32_32x32x16_bf16):
//   A: row = lane&31, k = 8*(lane>>5)+e     B: col = lane&31, k = 8*(lane>>5)+e
//   D: col = lane&31, row = (reg&3) + 8*(reg>>2) + 4*(lane>>5)
template<int NOUT, int K>
__device__ __forceinline__ void gemm_dual_mfma_body(
    const float* __restrict__ X,
    const short* __restrict__ BH, const short* __restrict__ BL,
    const float* __restrict__ b1, const float* __restrict__ b2,
    _Float16* __restrict__ Y1, _Float16* __restrict__ Y2, int N, int bid)
{
  constexpr int BN     = 2 * NOUT;
  constexpr int KSTEPS = (K + 15) / 16;
  constexpr int NR     = NOUT / 32;

  int tid   = threadIdx.x;
  int lane  = tid & 63;
  int wid   = tid >> 6;
  int wm    = wid >> 1, wn = wid & 1;
  int llane = lane & 31, hlane = lane >> 5;
  int r0    = bid * 64;

  int arow  = r0 + wm * 32 + llane;
  bool rv   = arow < N;
  const float* px = X + (long)arow * K;

  s16x8 ah[KSTEPS], al[KSTEPS];
  #pragma unroll
  for (int ks = 0; ks < KSTEPS; ks++){
    int kg = (2 * ks + hlane) * 8;
    float v[8];
    #pragma unroll
    for (int e = 0; e < 8; e++)
      v[e] = (rv && kg + e < K) ? px[kg + e] : 0.f;
    #pragma unroll
    for (int e = 0; e < 8; e++){
      unsigned short h = f2bf(v[e]);
      ah[ks][e] = (short)h;
      al[ks][e] = (short)f2bf(v[e] - bf2f(h));
    }
  }

  f32x16 acc[NR];
  #pragma unroll
  for (int n = 0; n < NR; n++)
    #pragma unroll
    for (int i = 0; i < 16; i++) acc[n][i] = 0.f;

  const s16x8* BHf = (const s16x8*)BH;
  const s16x8* BLf = (const s16x8*)BL;
  #pragma unroll
  for (int ks = 0; ks < KSTEPS; ks++){
    long fb = (long)(2 * ks + hlane) * BN + wn * NOUT + llane;
    s16x8 bh[NR], bl[NR];
    #pragma unroll
    for (int n = 0; n < NR; n++){
      bh[n] = BHf[fb + n * 32];
      bl[n] = BLf[fb + n * 32];
    }
    #pragma unroll
    for (int n = 0; n < NR; n++)
      acc[n] = __builtin_amdgcn_mfma_f32_32x32x16_bf16(ah[ks], bh[n], acc[n], 0, 0, 0);
    #pragma unroll
    for (int n = 0; n < NR; n++)
      acc[n] = __builtin_amdgcn_mfma_f32_32x32x16_bf16(ah[ks], bl[n], acc[n], 0, 0, 0);
    #pragma unroll
    for (int n = 0; n < NR; n++)
      acc[n] = __builtin_amdgcn_mfma_f32_32x32x16_bf16(al[ks], bh[n], acc[n], 0, 0, 0);
  }

  const float* bsrc = wn ? b2 : b1;
  _Float16* Y = wn ? Y2 : Y1;
  #pragma unroll
  for (int n = 0; n < NR; n++){
    float bias = bsrc[n * 32 + llane];
    #pragma unroll
    for (int reg = 0; reg < 16; reg++){
      int row = r0 + wm * 32 + (reg & 3) + 8 * (reg >> 2) + 4 * hlane;
      if (row < N)
        Y[(long)row * NOUT + n * 32 + llane] = (_Float16)(acc[n][reg] + bias);
    }
  }
}

// ---------------------------------------------------------------- fused: base_assign || gemm1
// (R9: base_assign blocks [0,nb) do the block-scan prefix allocation (196
// atomics total); gemm1 blocks [nb, nb+gm) need only x + prepped weights from
// the previous dispatch. Independent -> one launch.)
__global__ __launch_bounds__(256) void base_gemm1_kernel(
    const int* __restrict__ deg, int* __restrict__ base,
    int* __restrict__ counter, int N, int nb,
    const float* __restrict__ X,
    const short* __restrict__ BH, const short* __restrict__ BL,
    const float* __restrict__ b1, const float* __restrict__ b2,
    _Float16* __restrict__ Y1, _Float16* __restrict__ Y2)
{
  __shared__ int wsum[4];
  __shared__ int bbase;
  int bid = blockIdx.x;
  if (bid >= nb){
    gemm_dual_mfma_body<128, 15>(X, BH, BL, b1, b2, Y1, Y2, N, bid - nb);
    return;
  }
  int n = bid * 256 + threadIdx.x;
  int d = (n < N) ? deg[n] : 0;
  int lane = threadIdx.x & 63;
  int wid  = threadIdx.x >> 6;
  int scan = d;
  #pragma unroll
  for (int o = 1; o < 64; o <<= 1){
    int t = __shfl_up(scan, o);
    if (lane >= o) scan += t;
  }
  if (lane == 63) wsum[wid] = scan;
  __syncthreads();
  if (threadIdx.x == 0){
    int tot = 0;
    #pragma unroll
    for (int i = 0; i < 4; i++){ int w = wsum[i]; wsum[i] = tot; tot += w; }
    bbase = atomicAdd(counter, tot);
  }
  __syncthreads();
  if (n < N) base[n] = bbase + wsum[wid] + scan - d;
}

// ea stored as broadcast half2 bits (h | h<<16) -- the agg reads it as
// f16x2 with zero per-edge conversion cost.
__global__ void fill_kernel(const int* __restrict__ ei, const float* __restrict__ ea,
                            const int* __restrict__ base, int* __restrict__ pos,
                            int2* __restrict__ csr_pack, int E){
  int e = blockIdx.x * blockDim.x + threadIdx.x;
  if (e >= E) return;
  int s = ei[e], d = ei[E + e];
  int p = atomicAdd(&pos[d], 1);
  _Float16 h = (_Float16)ea[e];
  unsigned int hb = (unsigned int)*(unsigned short*)&h;
  csr_pack[base[d] + p] = make_int2(s, (int)(hb | (hb << 16)));
}

// ---------------------------------------------------------------- packed-A MFMA dual GEMM (K=128)
// A comes prepacked in fragment order [kgroup][row][8k] (bf16 hi/lo), written by
// the previous layer's agg epilogue. Both operands are fully-coalesced 16B/lane
// streams; no LDS, no barriers, no in-kernel convert. fp16 outputs.
template<int NOUT>
__global__ __launch_bounds__(256) void gemm_dual_packed(
    const short* __restrict__ AH, const short* __restrict__ AL,
    const short* __restrict__ BH, const short* __restrict__ BL,
    const float* __restrict__ b1, const float* __restrict__ b2,
    _Float16* __restrict__ Y1, _Float16* __restrict__ Y2, int N)
{
  constexpr int BN     = 2 * NOUT;
  constexpr int KSTEPS = 8;                 // K = 128
  constexpr int NR     = NOUT / 32;

  int tid   = threadIdx.x;
  int lane  = tid & 63;
  int wid   = tid >> 6;
  int wm    = wid >> 1, wn = wid & 1;
  int llane = lane & 31, hlane = lane >> 5;
  int r0    = blockIdx.x * 64;
  int arow  = r0 + wm * 32 + llane;
  int ar    = arow < N ? arow : N - 1;      // clamp: extra rows never stored

  const s16x8* AHf = (const s16x8*)AH;
  const s16x8* ALf = (const s16x8*)AL;
  const s16x8* BHf = (const s16x8*)BH;
  const s16x8* BLf = (const s16x8*)BL;

  f32x16 acc[NR];
  #pragma unroll
  for (int n = 0; n < NR; n++)
    #pragma unroll
    for (int i = 0; i < 16; i++) acc[n][i] = 0.f;

  #pragma unroll
  for (int ks = 0; ks < KSTEPS; ks++){
    long fa = (long)(2 * ks + hlane) * N + ar;
    s16x8 ah = AHf[fa];
    s16x8 al = ALf[fa];
    long fb = (long)(2 * ks + hlane) * BN + wn * NOUT + llane;
    s16x8 bh[NR], bl[NR];
    #pragma unroll
    for (int n = 0; n < NR; n++){
      bh[n] = BHf[fb + n * 32];
      bl[n] = BLf[fb + n * 32];
    }
    #pragma unroll
    for (int n = 0; n < NR; n++)
      acc[n] = __builtin_amdgcn_mfma_f32_32x32x16_bf16(ah, bh[n], acc[n], 0, 0, 0);
    #pragma unroll
    for (int n = 0; n < NR; n++)
      acc[n] = __builtin_amdgcn_mfma_f32_32x32x16_bf16(ah, bl[n], acc[n], 0, 0, 0);
    #pragma unroll
    for (int n = 0; n < NR; n++)
      acc[n] = __builtin_amdgcn_mfma_f32_32x32x16_bf16(al, bh[n], acc[n], 0, 0, 0);
  }

  const float* bsrc = wn ? b2 : b1;
  _Float16* Y = wn ? Y2 : Y1;
  #pragma unroll
  for (int n = 0; n < NR; n++){
    float bias = bsrc[n * 32 + llane];
    #pragma unroll
    for (int reg = 0; reg < 16; reg++){
      int row = r0 + wm * 32 + (reg & 3) + 8 * (reg >> 2) + 4 * hlane;
      if (row < N)
        Y[(long)row * NOUT + n * 32 + llane] = (_Float16)(acc[n][reg] + bias);
    }
  }
}

// ---------------------------------------------------------------- fused edge softmax + aggregation
// R9: EXACT revert to the R6-best shape (58.3us, 479.9 total): 4 ch/lane,
// LPE=32 (C=16), ES=2, NP=4, B=8, VGPR 40. R7 (CPL=8,NP=2: 71us) and R8
// (CPL=8,NP=4: 78us, VGPR 64) both lost occupancy; measured dur*occupancy is
// ~constant across R6/R7/R8 -> agg is latency-bound, throughput ~ resident
// waves. The R6 shape maximizes occupancy (VGPR 40) with 8-deep load batching.
// NOTE (R1): loads stay unconditional+batched; no predication on tail.
template<int C>
__global__ __launch_bounds__(512) void agg_kernel(
    const _Float16* __restrict__ xl, const _Float16* __restrict__ xr,
    const int* __restrict__ base, const int* __restrict__ deg,
    const int2* __restrict__ csr_pack,
    const float* __restrict__ We, const float* __restrict__ att,
    const float* __restrict__ bias, float* __restrict__ hout,
    short* __restrict__ packH, short* __restrict__ packL,
    const float* __restrict__ Wlin, const float* __restrict__ blin,
    float* __restrict__ outF, int N, int do_elu)
{
  constexpr int HC  = 8 * C;
  constexpr int LPH = C / 4;       // lanes per head
  constexpr int LPE = 8 * LPH;     // lanes per edge (32 or 16)
  constexpr int ES  = 64 / LPE;    // edge slots per pass (2 or 4)
  constexpr int NP  = 4;           // passes per iteration
  constexpr int B   = ES * NP;     // edges per iteration (8 or 16)

  int lane = threadIdx.x & 63;
  int wv   = blockIdx.x * (blockDim.x >> 6) + (threadIdx.x >> 6);
  int nwv  = gridDim.x * (blockDim.x >> 6);
  int slot = lane / LPE;           // edge slot within pass
  int hl   = lane % LPE;           // position within edge
  int coff = hl * 4;               // channel offset: h*C + g*4 == hl*4

  float4 attf = *(const float4*)(att  + coff);
  float4 wevf = *(const float4*)(We   + coff);
  float4 bv   = *(const float4*)(bias + coff);
  float4 wl   = outF ? *(const float4*)(Wlin + coff) : make_float4(0.f,0.f,0.f,0.f);

  f16x2 a01 = { (_Float16)attf.x, (_Float16)attf.y };
  f16x2 a23 = { (_Float16)attf.z, (_Float16)attf.w };
  f16x2 w01 = { (_Float16)wevf.x, (_Float16)wevf.y };
  f16x2 w23 = { (_Float16)wevf.z, (_Float16)wevf.w };
  f16x2 sl2 = { (_Float16)NEG_SLOPE, (_Float16)NEG_SLOPE };

  for (int n = wv; n < N; n += nwv){
    f16x4 xr4 = *(const f16x4*)(xr + (long)n * HC + coff);
    f16x2 x01 = __builtin_shufflevector(xr4, xr4, 0, 1);
    f16x2 x23 = __builtin_shufflevector(xr4, xr4, 2, 3);
    float4 acc = {0.f, 0.f, 0.f, 0.f};
    float lrun = 0.f;
    int s0 = base[n], end = s0 + deg[n];

    for (int s = s0; s < end; s += B){
      int2 pk[NP]; bool val[NP];
      #pragma unroll
      for (int t = 0; t < NP; t++){
        int idx = s + t * ES + slot;
        val[t] = idx < end;
        pk[t]  = csr_pack[val[t] ? idx : s0];
      }
      f16x4 rh[NP];
      #pragma unroll
      for (int t = 0; t < NP; t++)
        rh[t] = *(const f16x4*)(xl + (long)pk[t].x * HC + coff);
      #pragma unroll
      for (int t = 0; t < NP; t++){
        f16x2 r01 = __builtin_shufflevector(rh[t], rh[t], 0, 1);
        f16x2 r23 = __builtin_shufflevector(rh[t], rh[t], 2, 3);
        f16x2 ev  = *(const f16x2*)&pk[t].y;      // broadcast half2
        f16x2 t01 = r01 + (ev * w01 + x01);
        f16x2 t23 = r23 + (ev * w23 + x23);
        f16x2 m01 = __builtin_elementwise_max(t01, t01 * sl2);
        f16x2 m23 = __builtin_elementwise_max(t23, t23 * sl2);
        float p = __builtin_amdgcn_fdot2(m01, a01,
                  __builtin_amdgcn_fdot2(m23, a23, 0.f, false), false);
        #pragma unroll
        for (int o = 1; o < LPH; o <<= 1) p += __shfl_xor(p, o);
        float pe = val[t] ? __expf(p) : 0.f;
        lrun  += pe;
        acc.x += pe * (float)r01[0];
        acc.y += pe * (float)r01[1];
        acc.z += pe * (float)r23[0];
        acc.w += pe * (float)r23[1];
      }
    }
    // reduce over edge slots
    #pragma unroll
    for (int o = LPE; o < 64; o <<= 1){
      lrun  += __shfl_xor(lrun, o);
      acc.x += __shfl_xor(acc.x, o);
      acc.y += __shfl_xor(acc.y, o);
      acc.z += __shfl_xor(acc.z, o);
      acc.w += __shfl_xor(acc.w, o);
    }
    float inv = 1.f / (lrun + 1e-16f);
    float4 o4;
    o4.x = acc.x * inv + bv.x;
    o4.y = acc.y * inv + bv.y;
    o4.z = acc.z * inv + bv.z;
    o4.w = acc.w * inv + bv.w;
    if (do_elu){
      o4.x = o4.x > 0.f ? o4.x : (__expf(o4.x) - 1.f);
      o4.y = o4.y > 0.f ? o4.y : (__expf(o4.y) - 1.f);
      o4.z = o4.z > 0.f ? o4.z : (__expf(o4.z) - 1.f);
      o4.w = o4.w > 0.f ? o4.w : (__expf(o4.w) - 1.f);
    }
    if (outF){
      // fused final linear: out[n] = sum_c o_c * Wlin_c + blin
      float v = ((o4.x * wl.x + o4.y * wl.y) + (o4.z * wl.z + o4.w * wl.w));
      #pragma unroll
      for (int o = 1; o < LPE; o <<= 1) v += __shfl_xor(v, o);
      if (lane == 0) outF[n] = v + blin[0];
    } else if (packH){
      // write MFMA A-fragments: element (kg,row,e) at shorts idx (kg*N+row)*8+e
      // lane hl holds k = hl*4 .. hl*4+3  ->  kg = hl>>1, e0 = (hl&1)*4
      if (slot == 0){
        unsigned short h0 = f2bf(o4.x), h1 = f2bf(o4.y),
                       h2 = f2bf(o4.z), h3 = f2bf(o4.w);
        s16x4 hv = { (short)h0, (short)h1, (short)h2, (short)h3 };
        s16x4 lv = { (short)f2bf(o4.x - bf2f(h0)), (short)f2bf(o4.y - bf2f(h1)),
                     (short)f2bf(o4.z - bf2f(h2)), (short)f2bf(o4.w - bf2f(h3)) };
        long idx = ((long)(hl >> 1) * N + n) * 8 + (hl & 1) * 4;
        *(s16x4*)(packH + idx) = hv;
        *(s16x4*)(packL + idx) = lv;
      }
    } else {
      if (slot == 0)
        *(float4*)(hout + (long)n * HC + coff) = o4;
    }
  }
}

// ----------------------------------------------------------------
extern "C" void kernel_launch(void* const* d_in, const int* in_sizes, int n_in,
                              void* d_out, int out_size, void* d_ws, size_t ws_size,
                              hipStream_t stream)
{
  const float* x  = (const float*)d_in[0];
  const float* ea = (const float*)d_in[1];
  const int*   ei = (const int*)d_in[2];
  const int N = in_sizes[0] / 15;
  const int E = in_sizes[1];

  const float* P[28];
  for (int i = 0; i < 28; i++) P[i] = (const float*)d_in[3 + i];
  const float* Wlin = (const float*)d_in[31];
  const float* blin = (const float*)d_in[32];

  size_t off = 0;
  auto carve = [&](size_t bytes) -> char* {
    char* p = (char*)d_ws + off;
    off = (off + bytes + 255) & ~(size_t)255;
    return p;
  };
  // meta layout (R9): deg[N], pos[N], counter[1] contiguous -> ONE memset;
  // base[N] needs no init.
  int*   meta     = (int*)  carve(sizeof(int)  * (size_t)(3 * N + 64));
  int*   deg      = meta;                // [N] zeroed
  int*   pos      = meta + N;            // [N] zeroed
  int*   counter  = meta + 2 * N;        // [1] zeroed
  int*   base     = meta + 2 * N + 64;   // [N]
  int2*  csr_pack = (int2*) carve(sizeof(int2) * (size_t)E);
  _Float16* xl    = (_Float16*)carve(sizeof(_Float16) * (size_t)N * 128);
  _Float16* xr    = (_Float16*)carve(sizeof(_Float16) * (size_t)N * 128);
  short* pak_h    = (short*)carve(sizeof(short) * (size_t)N * 128);
  short* pak_l    = (short*)carve(sizeof(short) * (size_t)N * 128);
  // prepacked bf16 hi/lo weights, MFMA B-fragment order
  short* ph1 = (short*)carve(sizeof(short) * 4096);
  short* pl1 = (short*)carve(sizeof(short) * 4096);
  short* ph2 = (short*)carve(sizeof(short) * 32768);
  short* pl2 = (short*)carve(sizeof(short) * 32768);
  short* ph3 = (short*)carve(sizeof(short) * 32768);
  short* pl3 = (short*)carve(sizeof(short) * 32768);
  short* ph4 = (short*)carve(sizeof(short) * 16384);
  short* pl4 = (short*)carve(sizeof(short) * 16384);

  hipMemsetAsync(deg, 0, sizeof(int) * (size_t)(2 * N + 1), stream);

  int eb = (E + 255) / 256;
  int nb = (N + 255) / 256;
  int gm = (N + 63) / 64;     // 64-row MFMA tiles
  int agrid = 2048;           // agg: grid-stride, 8 waves/block

  // dispatch 2: deg_count || weight prep (independent)
  deg_prep_kernel<<<eb + 42, 256, 0, stream>>>(ei + E, deg, E, eb,
                                               P[0],  P[2],  ph1, pl1,
                                               P[7],  P[9],  ph2, pl2,
                                               P[14], P[16], ph3, pl3,
                                               P[21], P[23], ph4, pl4);
  // dispatch 3: base_assign || gemm1 (independent; both deps from dispatch 2)
  base_gemm1_kernel<<<nb + gm, 256, 0, stream>>>(deg, base, counter, N, nb,
                                                 x, ph1, pl1, P[1], P[3], xl, xr);
  // dispatch 4: CSR fill
  fill_kernel<<<eb, 256, 0, stream>>>(ei, ea, base, pos, csr_pack, E);

  // layer 1 agg; writes packed A for gemm2
  agg_kernel<16><<<agrid, 512, 0, stream>>>(xl, xr, base, deg, csr_pack, P[4], P[5], P[6],
                                            nullptr, pak_h, pak_l,
                                            nullptr, nullptr, nullptr, N, 1);
  // layer 2
  gemm_dual_packed<128><<<gm, 256, 0, stream>>>(pak_h, pak_l, ph2, pl2, P[8], P[10], xl, xr, N);
  agg_kernel<16><<<agrid, 512, 0, stream>>>(xl, xr, base, deg, csr_pack, P[11], P[12], P[13],
                                            nullptr, pak_h, pak_l,
                                            nullptr, nullptr, nullptr, N, 1);
  // layer 3
  gemm_dual_packed<128><<<gm, 256, 0, stream>>>(pak_h, pak_l, ph3, pl3, P[15], P[17], xl, xr, N);
  agg_kernel<16><<<agrid, 512, 0, stream>>>(xl, xr, base, deg, csr_pack, P[18], P[19], P[20],
                                            nullptr, pak_h, pak_l,
                                            nullptr, nullptr, nullptr, N, 1);
  // layer 4: H*C=64, no ELU + fused final linear 64->1
  gemm_dual_packed<64><<<gm, 256, 0, stream>>>(pak_h, pak_l, ph4, pl4, P[22], P[24], xl, xr, N);
  agg_kernel<8><<<agrid, 512, 0, stream>>>(xl, xr, base, deg, csr_pack, P[25], P[26], P[27],
                                           nullptr, nullptr, nullptr,
                                           Wlin, blin, (float*)d_out, N, 0);
}